// Round 7
// baseline (112.666 us; speedup 1.0000x reference)
//
#include <hip/hip_runtime.h>
#include <math.h>
#include <stdint.h>

#define NBATCH 2
#define KBOX   512
#define NBOX   (NBATCH*KBOX)
#define CCH    256
#define NBIN   49                 // 7x7 bins
#define NCH    8                  // channels per block (kernel 2)
#define BPB    (CCH/NCH)          // 32 blocks per box
#define COUT   (CCH*NBIN)         // 12544 outputs per box
#define WCAP   1152               // per-channel window capacity; proven max ~976
#define HDRN   8                  // ints per box header
#define TAPN   (24*NBIN)          // 1176 words per box tap table

typedef const uint32_t __attribute__((address_space(1)))* gas_u32p;
typedef uint32_t       __attribute__((address_space(3)))* las_u32p;

// ---------------- kernel 1: per-box header + tap table (once) ----------------
__global__ __launch_bounds__(64) void box_prep_kernel(
    const float* __restrict__ boxes, int* __restrict__ hdr, int* __restrict__ taps)
{
    const int m    = blockIdx.x;
    const int lane = threadIdx.x;

    const float x1 = boxes[m*4+0];
    const float y1 = boxes[m*4+1];
    const float x2 = boxes[m*4+2];
    const float y2 = boxes[m*4+3];

    const float area = (x2 - x1) * (y2 - y1);
    const float size = sqrtf(area);
    float lvlf = floorf(4.0f + log2f(size / 224.0f + 1e-8f));
    lvlf = fminf(fmaxf(lvlf, 2.0f), 5.0f);
    const int lvl = (int)lvlf - 2;    // 0..3

    const int   H     = 256 >> lvl;
    const float scale = 0.25f / (float)(1 << lvl);
    const float Hf    = (float)H;

    const float bx1 = x1 * scale - 0.5f;
    const float by1 = y1 * scale - 0.5f;
    const float bin_w = (x2 * scale - 0.5f - bx1) / 7.0f;
    const float bin_h = (y2 * scale - 0.5f - by1) / 7.0f;

    // window bounds (same clamp math as taps -> taps provably inside)
    const float sx_min = bx1 + 0.25f * bin_w;
    const float sx_max = bx1 + 6.75f * bin_w;
    const float sy_min = by1 + 0.25f * bin_h;
    const float sy_max = by1 + 6.75f * bin_h;
    const int wx0 = min((int)floorf(fmaxf(sx_min, 0.0f)), H - 1);
    const int wy0 = min((int)floorf(fmaxf(sy_min, 0.0f)), H - 1);
    const int wx1 = min(min((int)floorf(fmaxf(sx_max, 0.0f)), H - 1) + 1, H - 1);
    const int wy1 = min(min((int)floorf(fmaxf(sy_max, 0.0f)), H - 1) + 1, H - 1);
    const int wspan = wx1 - wx0 + 1;
    const int hspan = wy1 - wy0 + 1;
    const int wsz   = wspan * hspan;

    if (lane < NBIN) {
        const int py = lane / 7;
        const int px = lane - py * 7;
        const int base = m * TAPN;
        float* tapf = (float*)taps;

        #pragma unroll
        for (int s = 0; s < 4; ++s) {
            const int iy = s >> 1;
            const int ix = s & 1;
            const float gy = ((float)(2*py + iy) + 0.5f) * 0.5f;
            const float gx = ((float)(2*px + ix) + 0.5f) * 0.5f;
            const float yy = by1 + gy * bin_h;
            const float xx = bx1 + gx * bin_w;

            const bool valid = (yy >= -1.0f) && (yy <= Hf) && (xx >= -1.0f) && (xx <= Hf);

            const float yc = fmaxf(yy, 0.0f);
            const float xc = fmaxf(xx, 0.0f);
            int yl = min((int)floorf(yc), H - 1);
            int xl = min((int)floorf(xc), H - 1);
            const int yh = min(yl + 1, H - 1);
            const int xh = min(xl + 1, H - 1);
            const float fy = yc - (float)yl;
            float fx = xc - (float)xl;
            if (xh == xl) fx = 0.0f;   // clamped x-pair: hi weight 0 (exact)

            const float vm  = valid ? 0.25f : 0.0f;   // fold 2x2 mean into weights
            const float wyl = (1.0f - fy) * vm;
            const float wyh = fy * vm;

            const int xr = xl - wx0;
            const int o_lo = (yl - wy0) * wspan + xr;
            const int o_hi = (yh - wy0) * wspan + xr;

            taps[base + (2*s  )*NBIN + lane] = o_lo;
            taps[base + (2*s+1)*NBIN + lane] = o_hi;
            tapf[base + (8 + 2*s  )*NBIN + lane] = wyl * (1.0f - fx);
            tapf[base + (8 + 2*s+1)*NBIN + lane] = wyh * (1.0f - fx);
            tapf[base + (16 + 2*s  )*NBIN + lane] = wyl * fx;
            tapf[base + (16 + 2*s+1)*NBIN + lane] = wyh * fx;
        }
    }

    if (lane == 0) {
        int* h = hdr + m * HDRN;
        h[0] = lvl;
        h[1] = H;
        h[2] = H * H;
        h[3] = wy0 * H + wx0;
        h[4] = wspan;
        h[5] = wsz;
    }
}

// ---------------- kernel 2: stage window to LDS, bilinear from LDS ----------------
__global__ __launch_bounds__(256, 4) void roi_align_kernel(
    const float* __restrict__ f2, const float* __restrict__ f3,
    const float* __restrict__ f4, const float* __restrict__ f5,
    const int* __restrict__ hdr, const int* __restrict__ taps,
    float* __restrict__ out)
{
    const int bid  = blockIdx.x;
    const int m    = bid >> 5;        // box index (BPB == 32)
    const int cg   = bid & 31;        // channel group within box
    const int tid  = threadIdx.x;
    const int lane = tid & 63;
    const int wid  = tid >> 6;
    const int b    = m >> 9;          // batch index (KBOX == 512)

    __shared__ float win[NCH * WCAP];

    const int* h = hdr + m * HDRN;
    const int lvl   = h[0];
    const int H     = h[1];
    const int HH    = h[2];
    const int woff  = h[3];
    const int wspan = h[4];
    const int wsz   = h[5];

    const float* fptr = (lvl == 0) ? f2 : (lvl == 1) ? f3 : (lvl == 2) ? f4 : f5;
    const int c0 = cg * NCH;
    const float* src0 = fptr + ((size_t)(b * CCH + c0)) * HH + woff;

    // ---- stage: one (r,col) decode per element, 8 channels amortized ----
    for (int i = tid; i < wsz; i += 256) {
        const int r   = i / wspan;
        const int col = i - r * wspan;
        const float* sp = src0 + r * H + col;
        const int ldsbase = i & ~63;          // wave-uniform (lane = i & 63)
        #pragma unroll
        for (int c = 0; c < NCH; ++c) {
            __builtin_amdgcn_global_load_lds(
                (gas_u32p)(const void*)(sp + (size_t)c * HH),
                (las_u32p)(void*)(&win[c * WCAP + ldsbase]),
                4, 0, 0);
        }
    }
    // sentinel: one-past-end element a clamped x-hi pair read may touch (weight 0)
    if (tid < NCH) win[tid * WCAP + wsz] = 0.0f;

    // ---- load precomputed taps: 24 coalesced dword loads per lane ----
    const int lidx = (lane < NBIN) ? lane : NBIN - 1;
    const int tb = m * TAPN;
    const float* tf = (const float*)taps;

    int   o8 [8];
    float wlo[8];
    float whi[8];
    #pragma unroll
    for (int j = 0; j < 8; ++j) o8 [j] = taps[tb + j*NBIN + lidx];
    #pragma unroll
    for (int j = 0; j < 8; ++j) wlo[j] = tf[tb + (8  + j)*NBIN + lidx];
    #pragma unroll
    for (int j = 0; j < 8; ++j) whi[j] = tf[tb + (16 + j)*NBIN + lidx];

    __syncthreads();

    // ---- compute: each wave owns 2 channels; adjacent-pair LDS reads ----
    const float* wa = win + (wid * 2    ) * WCAP;
    const float* wb = win + (wid * 2 + 1) * WCAP;

    float acc0 = 0.0f, acc1 = 0.0f;
    #pragma unroll
    for (int j = 0; j < 8; ++j) {
        const int oj = o8[j];
        const float a_lo = wa[oj], a_hi = wa[oj + 1];
        const float b_lo = wb[oj], b_hi = wb[oj + 1];
        acc0 += wlo[j] * a_lo + whi[j] * a_hi;
        acc1 += wlo[j] * b_lo + whi[j] * b_hi;
    }

    if (lane < NBIN) {
        float* outp = out + (size_t)m * COUT + (size_t)(c0 + wid * 2) * NBIN + lane;
        __builtin_nontemporal_store(acc0, outp);
        __builtin_nontemporal_store(acc1, outp + NBIN);
    }
}

extern "C" void kernel_launch(void* const* d_in, const int* in_sizes, int n_in,
                              void* d_out, int out_size, void* d_ws, size_t ws_size,
                              hipStream_t stream) {
    const float* f2    = (const float*)d_in[0];
    const float* f3    = (const float*)d_in[1];
    const float* f4    = (const float*)d_in[2];
    const float* f5    = (const float*)d_in[3];
    const float* boxes = (const float*)d_in[4];
    float* outp = (float*)d_out;

    int* hdr  = (int*)d_ws;                    // 1024*8*4   = 32 KB
    int* taps = (int*)d_ws + NBOX * HDRN;      // 1024*1176*4 ≈ 4.82 MB

    box_prep_kernel<<<dim3(NBOX), dim3(64), 0, stream>>>(boxes, hdr, taps);
    roi_align_kernel<<<dim3(NBOX * BPB), dim3(256), 0, stream>>>(
        f2, f3, f4, f5, hdr, taps, outp);
}